// Round 3
// baseline (703.294 us; speedup 1.0000x reference)
//
#include <hip/hip_runtime.h>

// ======================================================================
// Involution net: 3 x (1x1 conv + dynamic-kernel apply w/ batch BN) + FC
// B=1024, fp32 reference. R6 = R5 re-audited + workspace-overflow fix.
//
// - R4 fusion: p3(lN) fused into p1(lN+1) and p3(l3) into FC; out1..3
//   live only in LDS. 5 compute launches + 2 tiny preps.
// - R5 MFMA: p1_l1 (M=128,N=256,K=200 per batch; 13.1 of 17.7 GFLOP)
//   via 3x mfma_f32_16x16x32_bf16 split precision (wH*xH + wH*xL + wL*xH,
//   fp32 accum; dropped wL*xL ~ 2^-18 rel). Weights pre-packed into
//   per-lane A-frags (hi/lo); x transposed per 32-chan chunk into LDS
//   B-frag slots, each staging thread writing ONE contiguous 16B slot
//   (ds_write_b128/ds_read_b128 lane-consecutive, conflict-free).
// - R6 fix: apkh/apkl alias the XI2 region (dead until f2 writes it;
//   kernel-boundary ordering prep_apk -> p1_l1_mfma -> f2). Workspace
//   high-water = 31,565,696 floats, exactly the R3-proven footprint.
// ======================================================================

typedef __attribute__((ext_vector_type(8))) short short8v;   // 8 bf16 bit-patterns
typedef __attribute__((ext_vector_type(4))) float f32x4;

__device__ __forceinline__ unsigned short f2bf_rne(float x) {
    unsigned u = __float_as_uint(x);
    unsigned r = u + 0x7FFFu + ((u >> 16) & 1u);
    return (unsigned short)(r >> 16);
}
__device__ __forceinline__ float bf2f(unsigned short h) {
    return __uint_as_float(((unsigned)h) << 16);
}

static constexpr size_t OFF_WCAT1 = 0;        // unused by MFMA path (kept: zero-risk)
static constexpr size_t OFF_WCAT2 = 25600;
static constexpr size_t OFF_WCAT3 = 41984;
static constexpr size_t OFF_SUM1  = 107520;   // 896 stat floats start here
static constexpr size_t OFF_SQS1  = 107584;
static constexpr size_t OFF_SUM2  = 107648;
static constexpr size_t OFF_SQS2  = 107776;
static constexpr size_t OFF_SUM3  = 107904;
static constexpr size_t OFF_SQS3  = 108160;
static constexpr size_t OFF_XI1   = 108416;     // 16777216 floats (also xi3)
static constexpr size_t OFF_RPRE1 = 16885632;   //  4194304 floats (also rpre3)
static constexpr size_t OFF_XI2   = 21079936;   //  8388608 floats
static constexpr size_t OFF_RPRE2 = 29468544;   //  2097152 floats -> end 31565696
// apk A-fragments alias the (not-yet-live) XI2 region:
static constexpr size_t OFF_APKH  = OFF_XI2;            // ushort[28672] = 14336 floats
static constexpr size_t OFF_APKL  = OFF_XI2 + 14336;    // ushort[28672]

// ---------------- weight concat+transpose prep + stat zero ----------------
__global__ void prep_all(const float* __restrict__ wi1, const float* __restrict__ wr1,
                         const float* __restrict__ wi2, const float* __restrict__ wr2,
                         const float* __restrict__ wi3, const float* __restrict__ wr3,
                         float* __restrict__ ws) {
    int e = blockIdx.x * 256 + threadIdx.x;
    if (e >= 108416) return;
    if (e >= 107520) { ws[e] = 0.f; return; }     // BN stat accumulators
    const float* wi; const float* wr; float* wt; int cin, cout;
    if (e < 25600)      { wi = wi1; wr = wr1; wt = ws + OFF_WCAT1; cin = 200; cout = 64; }
    else if (e < 41984) { e -= 25600; wi = wi2; wr = wr2; wt = ws + OFF_WCAT2; cin = 64;  cout = 128; }
    else                { e -= 41984; wi = wi3; wr = wr3; wt = ws + OFF_WCAT3; cin = 128; cout = 256; }
    int M = 2 * cout, c = e / M, m = e % M;
    wt[e] = (m < cout) ? wi[m * cin + c] : wr[(m - cout) * cin + c];
}

// ---------------- A-fragment packing for p1_l1 MFMA ----------------
// aPk[ck][mt][lane][v] = bf16 of Wcat[16*mt + (lane&15)][32*ck + 8*(lane>>4) + v]
// (Wcat row m<64 -> W_init1, else W_red1; zero-pad c>=200). hi and lo arrays.
__global__ void prep_apk(const float* __restrict__ wi1, const float* __restrict__ wr1,
                         unsigned short* __restrict__ ah, unsigned short* __restrict__ al) {
    int e = blockIdx.x * 256 + threadIdx.x;
    if (e >= 28672) return;
    int v  = e & 7;
    int l  = (e >> 3) & 63;
    int mt = (e >> 9) & 7;
    int ck = e >> 12;
    int c = 32 * ck + ((l >> 4) << 3) + v;
    int m = 16 * mt + (l & 15);
    float wv = 0.f;
    if (c < 200) wv = (m < 64) ? wi1[m * 200 + c] : wr1[(m - 64) * 200 + c];
    unsigned short h = f2bf_rne(wv);
    ah[e] = h;
    al[e] = f2bf_rne(wv - bf2f(h));
}

// ---------------- P1 layer 1 via split-bf16 MFMA ----------------
// Per block (batch b): D[128][256] = Wcat[128][200] * x[b][200][256].
// 512 thr = 8 waves; wave w owns m-tile w (rows 16w..16w+15), all 16 n-tiles.
// K padded to 224 = 7 chunks of 32. acc: 16 x f32x4 per lane.
// C/D: col = lane&15 (n within tile), row = 4*(lane>>4)+reg (m within tile).
__global__ __launch_bounds__(512) void p1_l1_mfma(
    const float* __restrict__ x,      // [B][200][256]
    const unsigned short* __restrict__ aHiG,
    const unsigned short* __restrict__ aLoG,
    float* __restrict__ xi,           // [B][64][256]
    float* __restrict__ rpre,         // [B][64][64]
    float* __restrict__ ssum, float* __restrict__ ssqs)
{
    __shared__ __align__(16) unsigned short bHi[8192];  // [nt][lane][8]
    __shared__ __align__(16) unsigned short bLo[8192];
    const int tid = threadIdx.x, b = blockIdx.x;
    const int lane = tid & 63, w = tid >> 6;
    const float* xb = x + (size_t)b * 200 * 256;

    f32x4 acc[16];
    #pragma unroll
    for (int i = 0; i < 16; ++i) acc[i] = f32x4{0.f, 0.f, 0.f, 0.f};

    // staging: slot s (0..1023): nt=s>>6, l=s&63 holds
    // x[c0 + 8*(l>>4) + j][16*(s>>6) + (l&15)], j=0..7  (B-fragment layout)
    float v0[8], v1[8];
    auto load_slot = [&](int s, int c0, float* v) {
        int l = s & 63;
        int n = (((s >> 6) << 4)) | (l & 15);
        int cb = c0 + ((l >> 4) << 3);
        #pragma unroll
        for (int j = 0; j < 8; ++j) {
            int c = cb + j;
            v[j] = (c < 200) ? xb[c * 256 + n] : 0.f;
        }
    };
    auto write_slot = [&](int s, const float* v) {
        unsigned short h[8], g[8];
        #pragma unroll
        for (int j = 0; j < 8; ++j) {
            h[j] = f2bf_rne(v[j]);
            g[j] = f2bf_rne(v[j] - bf2f(h[j]));
        }
        uint4 ph, pl;
        ph.x = (unsigned)h[0] | ((unsigned)h[1] << 16);
        ph.y = (unsigned)h[2] | ((unsigned)h[3] << 16);
        ph.z = (unsigned)h[4] | ((unsigned)h[5] << 16);
        ph.w = (unsigned)h[6] | ((unsigned)h[7] << 16);
        pl.x = (unsigned)g[0] | ((unsigned)g[1] << 16);
        pl.y = (unsigned)g[2] | ((unsigned)g[3] << 16);
        pl.z = (unsigned)g[4] | ((unsigned)g[5] << 16);
        pl.w = (unsigned)g[6] | ((unsigned)g[7] << 16);
        *(uint4*)(bHi + (size_t)s * 8) = ph;
        *(uint4*)(bLo + (size_t)s * 8) = pl;
    };

    load_slot(tid, 0, v0);
    load_slot(tid + 512, 0, v1);

    for (int ck = 0; ck < 7; ++ck) {
        write_slot(tid, v0);
        write_slot(tid + 512, v1);
        __syncthreads();
        if (ck < 6) {            // T14: issue next chunk's loads before MFMA cluster
            load_slot(tid, 32 * (ck + 1), v0);
            load_slot(tid + 512, 32 * (ck + 1), v1);
        }
        const size_t abase = ((size_t)(ck * 8 + w) * 64 + lane) * 8;
        short8v aH = *(const short8v*)(aHiG + abase);
        short8v aL = *(const short8v*)(aLoG + abase);
        #pragma unroll
        for (int nt = 0; nt < 16; ++nt) {
            short8v bH = *(const short8v*)(bHi + ((size_t)(nt * 64 + lane)) * 8);
            short8v bL = *(const short8v*)(bLo + ((size_t)(nt * 64 + lane)) * 8);
            acc[nt] = __builtin_amdgcn_mfma_f32_16x16x32_bf16(aH, bH, acc[nt], 0, 0, 0);
            acc[nt] = __builtin_amdgcn_mfma_f32_16x16x32_bf16(aH, bL, acc[nt], 0, 0, 0);
            acc[nt] = __builtin_amdgcn_mfma_f32_16x16x32_bf16(aL, bH, acc[nt], 0, 0, 0);
        }
        __syncthreads();
    }

    // epilogue. nt is spatial row h (n = 16*nt + col), col = lane&15.
    const int g = lane >> 4, col = lane & 15;
    if (w < 4) {
        // rows m = 16w + 4g + r  -> xi
        float* xr = xi + ((size_t)b * 64 + 16 * w + 4 * g) * 256 + col;
        #pragma unroll
        for (int r = 0; r < 4; ++r)
            #pragma unroll
            for (int nt = 0; nt < 16; ++nt)
                xr[(size_t)r * 256 + nt * 16] = acc[nt][r];
    } else {
        // rows 64 + 16(w-4) + 4g + r -> 2x2 avg-pool + BN stats
        #pragma unroll
        for (int r = 0; r < 4; ++r) {
            const int mr = 16 * (w - 4) + 4 * g + r;
            float pv[8], s1 = 0.f, s2 = 0.f;
            #pragma unroll
            for (int ph = 0; ph < 8; ++ph) {
                float a0 = acc[2 * ph][r], a1 = acc[2 * ph + 1][r];
                float p = 0.25f * (a0 + __shfl_xor(a0, 1) + a1 + __shfl_xor(a1, 1));
                pv[ph] = p; s1 += p; s2 += p * p;
            }
            if ((col & 1) == 0) {
                float* rp = rpre + ((size_t)b * 64 + mr) * 64 + (col >> 1);
                #pragma unroll
                for (int ph = 0; ph < 8; ++ph) rp[ph * 8] = pv[ph];
            }
            s1 += __shfl_xor(s1, 2); s2 += __shfl_xor(s2, 2);
            s1 += __shfl_xor(s1, 4); s2 += __shfl_xor(s2, 4);
            s1 += __shfl_xor(s1, 8); s2 += __shfl_xor(s2, 8);
            if (col == 0) { atomicAdd(ssum + mr, s1); atomicAdd(ssqs + mr, s2); }
        }
    }
}

// ---------------- F2: p3(layer1) fused with p1_l2 ----------------
__global__ __launch_bounds__(256) void f2_kernel(
    const float* __restrict__ xi1,    // [B][64][256]
    const float* __restrict__ rpre1,  // [B][64][64]
    const float* __restrict__ ssum1, const float* __restrict__ ssqs1,
    const float* __restrict__ gamma1, const float* __restrict__ beta1,
    const float* __restrict__ wspan1, // [4][64]
    const float* __restrict__ wT2,    // [64][256]
    float* __restrict__ xi2,          // [B][128][64]
    float* __restrict__ rpre2,        // [B][128][16]
    float* __restrict__ ssum2, float* __restrict__ ssqs2)
{
    __shared__ float sc[64], sh[64];
    __shared__ float kl[4 * 64];
    __shared__ float rws[4096];   // rl in phase A, Ws chunk (16x256) in phase B
    __shared__ float Xl[4096];    // out1[b] = [64][64]
    const int tid = threadIdx.x, b = blockIdx.x;

    if (tid < 64) {
        float mean = ssum1[tid] * (1.f / 65536.f);
        float var  = ssqs1[tid] * (1.f / 65536.f) - mean * mean;
        float s    = gamma1[tid] * rsqrtf(var + 1e-5f);
        sc[tid] = s; sh[tid] = beta1[tid] - mean * s;
    }
    __syncthreads();
    const float* rp1 = rpre1 + (size_t)b * 4096;
    for (int e = tid; e < 4096; e += 256) {
        int o = e >> 6;
        rws[e] = fmaxf(fmaf(sc[o], rp1[e], sh[o]), 0.f);
    }
    __syncthreads();
    {
        int kk = tid >> 6, q = tid & 63;
        float s = 0.f;
        #pragma unroll
        for (int o = 0; o < 64; ++o)
            s = fmaf(wspan1[kk * 64 + o], rws[(o << 6) + q], s);
        kl[tid] = s;
    }
    __syncthreads();
    const float* xb1 = xi1 + (size_t)b * 64 * 256;
    for (int e = tid; e < 4096; e += 256) {
        int o = e >> 6, q = e & 63, ho = q >> 3, wo = q & 7;
        const float* p = xb1 + ((size_t)(o * 16 + 2 * ho)) * 16 + 2 * wo;
        float2 t  = *(const float2*)p;
        float2 bo = *(const float2*)(p + 16);
        Xl[e] = kl[q] * t.x + kl[64 + q] * t.y + kl[128 + q] * bo.x + kl[192 + q] * bo.y;
    }
    __syncthreads();

    const int tn = tid & 7, tm = tid >> 3;
    float acc[8][8];
    #pragma unroll
    for (int i = 0; i < 8; ++i)
        #pragma unroll
        for (int j = 0; j < 8; ++j) acc[i][j] = 0.f;

    for (int c0 = 0; c0 < 64; c0 += 16) {
        for (int e = tid * 4; e < 4096; e += 1024)
            *(float4*)(rws + e) = *(const float4*)(wT2 + (size_t)c0 * 256 + e);
        __syncthreads();
        #pragma unroll
        for (int c = 0; c < 16; ++c) {
            float4 xa = *(const float4*)(Xl + (c0 + c) * 64 + tn * 4);
            float4 xc = *(const float4*)(Xl + (c0 + c) * 64 + 32 + tn * 4);
            float4 wa = *(const float4*)(rws + c * 256 + tm * 4);
            float4 wb = *(const float4*)(rws + c * 256 + 128 + tm * 4);
            float xf[8] = {xa.x, xa.y, xa.z, xa.w, xc.x, xc.y, xc.z, xc.w};
            float wf[8] = {wa.x, wa.y, wa.z, wa.w, wb.x, wb.y, wb.z, wb.w};
            #pragma unroll
            for (int i = 0; i < 8; ++i)
                #pragma unroll
                for (int j = 0; j < 8; ++j)
                    acc[i][j] = fmaf(wf[i], xf[j], acc[i][j]);
        }
        __syncthreads();
    }

    const int gr = tm * 4;
    #pragma unroll
    for (int i = 0; i < 4; ++i) {
        float* dst = xi2 + ((size_t)b * 128 + gr + i) * 64 + tn * 4;
        float4 v0 = {acc[i][0], acc[i][1], acc[i][2], acc[i][3]};
        float4 v1 = {acc[i][4], acc[i][5], acc[i][6], acc[i][7]};
        *(float4*)dst = v0;
        *(float4*)(dst + 32) = v1;
    }
    const bool val = (tn & 2) == 0;
    #pragma unroll
    for (int i = 4; i < 8; ++i) {
        const int mr = gr + i - 4;
        float hp0 = acc[i][0] + acc[i][1], hp1 = acc[i][2] + acc[i][3];
        float hp2 = acc[i][4] + acc[i][5], hp3 = acc[i][6] + acc[i][7];
        float p0 = 0.25f * (hp0 + __shfl_xor(hp0, 2));
        float p1 = 0.25f * (hp1 + __shfl_xor(hp1, 2));
        float p2 = 0.25f * (hp2 + __shfl_xor(hp2, 2));
        float p3 = 0.25f * (hp3 + __shfl_xor(hp3, 2));
        float s1 = val ? (p0 + p1 + p2 + p3) : 0.f;
        float s2 = val ? (p0 * p0 + p1 * p1 + p2 * p2 + p3 * p3) : 0.f;
        if (val) {
            const int wo = (tn & 1) * 2, ho = tn >> 2;
            float* rp = rpre2 + ((size_t)b * 128 + mr) * 16;
            *(float2*)(rp + ho * 4 + wo) = float2{p0, p1};
            *(float2*)(rp + (2 + ho) * 4 + wo) = float2{p2, p3};
        }
        #pragma unroll
        for (int off = 1; off <= 4; off <<= 1) {
            s1 += __shfl_xor(s1, off); s2 += __shfl_xor(s2, off);
        }
        if (tn == 0) { atomicAdd(ssum2 + mr, s1); atomicAdd(ssqs2 + mr, s2); }
    }
}

// ---------------- F3: p3(layer2) fused with p1_l3 ----------------
__global__ __launch_bounds__(256) void f3_kernel(
    const float* __restrict__ xi2,    // [B][128][64]
    const float* __restrict__ rpre2,  // [B][128][16]
    const float* __restrict__ ssum2, const float* __restrict__ ssqs2,
    const float* __restrict__ gamma2, const float* __restrict__ beta2,
    const float* __restrict__ wspan2, // [4][128]
    const float* __restrict__ wT3,    // [128][512]
    float* __restrict__ xi3,          // [B][256][16]
    float* __restrict__ rpre3,        // [B][256][16]
    float* __restrict__ ssum3, float* __restrict__ ssqs3)
{
    __shared__ float sc[128], sh[128];
    __shared__ float kl[4 * 16];
    __shared__ float rws[8192];
    __shared__ float Xl[2048];
    const int tid = threadIdx.x, b = blockIdx.x;

    if (tid < 128) {
        float mean = ssum2[tid] * (1.f / 16384.f);
        float var  = ssqs2[tid] * (1.f / 16384.f) - mean * mean;
        float s    = gamma2[tid] * rsqrtf(var + 1e-5f);
        sc[tid] = s; sh[tid] = beta2[tid] - mean * s;
    }
    __syncthreads();
    const float* rp2 = rpre2 + (size_t)b * 2048;
    for (int e = tid; e < 2048; e += 256) {
        int o = e >> 4;
        rws[e] = fmaxf(fmaf(sc[o], rp2[e], sh[o]), 0.f);
    }
    __syncthreads();
    if (tid < 64) {
        int kk = tid >> 4, q = tid & 15;
        float s = 0.f;
        #pragma unroll
        for (int o = 0; o < 128; ++o)
            s = fmaf(wspan2[kk * 128 + o], rws[(o << 4) + q], s);
        kl[tid] = s;
    }
    __syncthreads();
    const float* xb2 = xi2 + (size_t)b * 128 * 64;
    for (int e = tid; e < 2048; e += 256) {
        int o = e >> 4, q = e & 15, ho = q >> 2, wo = q & 3;
        const float* p = xb2 + ((size_t)(o * 8 + 2 * ho)) * 8 + 2 * wo;
        float2 t  = *(const float2*)p;
        float2 bo = *(const float2*)(p + 8);
        Xl[e] = kl[q] * t.x + kl[16 + q] * t.y + kl[32 + q] * bo.x + kl[48 + q] * bo.y;
    }
    __syncthreads();

    const int tn = tid & 3, tm = tid >> 2;
    float acc[8][4];
    #pragma unroll
    for (int i = 0; i < 8; ++i)
        #pragma unroll
        for (int j = 0; j < 4; ++j) acc[i][j] = 0.f;

    for (int c0 = 0; c0 < 128; c0 += 16) {
        for (int e = tid * 4; e < 8192; e += 1024)
            *(float4*)(rws + e) = *(const float4*)(wT3 + (size_t)c0 * 512 + e);
        __syncthreads();
        #pragma unroll
        for (int c = 0; c < 16; ++c) {
            float4 xa = *(const float4*)(Xl + (c0 + c) * 16 + tn * 4);
            float4 wa = *(const float4*)(rws + c * 512 + tm * 4);
            float4 wb = *(const float4*)(rws + c * 512 + 256 + tm * 4);
            float xf[4] = {xa.x, xa.y, xa.z, xa.w};
            float wf[8] = {wa.x, wa.y, wa.z, wa.w, wb.x, wb.y, wb.z, wb.w};
            #pragma unroll
            for (int i = 0; i < 8; ++i)
                #pragma unroll
                for (int j = 0; j < 4; ++j)
                    acc[i][j] = fmaf(wf[i], xf[j], acc[i][j]);
        }
        __syncthreads();
    }

    const int gr = tm * 4;
    #pragma unroll
    for (int i = 0; i < 4; ++i) {
        float4 v0 = {acc[i][0], acc[i][1], acc[i][2], acc[i][3]};
        *(float4*)(xi3 + ((size_t)b * 256 + gr + i) * 16 + tn * 4) = v0;
    }
    #pragma unroll
    for (int i = 4; i < 8; ++i) {
        const int mr = gr + i - 4;
        float4 v0 = {acc[i][0], acc[i][1], acc[i][2], acc[i][3]};
        *(float4*)(rpre3 + ((size_t)b * 256 + mr) * 16 + tn * 4) = v0;
        float s1 = acc[i][0] + acc[i][1] + acc[i][2] + acc[i][3];
        float s2 = acc[i][0] * acc[i][0] + acc[i][1] * acc[i][1]
                 + acc[i][2] * acc[i][2] + acc[i][3] * acc[i][3];
        s1 += __shfl_xor(s1, 1); s2 += __shfl_xor(s2, 1);
        s1 += __shfl_xor(s1, 2); s2 += __shfl_xor(s2, 2);
        if (tn == 0) { atomicAdd(ssum3 + mr, s1); atomicAdd(ssqs3 + mr, s2); }
    }
}

// ---------------- F4: p3(layer3, k=3,s=1,pad=1) fused with FC ----------------
__global__ __launch_bounds__(256) void f4_kernel(
    const float* __restrict__ xi3,    // [B][256][16]
    const float* __restrict__ rpre3,  // [B][256][16]
    const float* __restrict__ ssum3, const float* __restrict__ ssqs3,
    const float* __restrict__ gamma3, const float* __restrict__ beta3,
    const float* __restrict__ wspan3, // [9][256]
    const float* __restrict__ wfc,    // [16][4096]
    const float* __restrict__ bfc,    // [16]
    float* __restrict__ out)          // [B][16]
{
    __shared__ float sc[256], sh[256];
    __shared__ float kl[9 * 16];
    __shared__ float xil[4096];
    __shared__ float rh[4096];
    __shared__ float red[4][16];
    const int tid = threadIdx.x, b = blockIdx.x;

    {
        float mean = ssum3[tid] * (1.f / 16384.f);
        float var  = ssqs3[tid] * (1.f / 16384.f) - mean * mean;
        float s    = gamma3[tid] * rsqrtf(var + 1e-5f);
        sc[tid] = s; sh[tid] = beta3[tid] - mean * s;
    }
    const float* xb3 = xi3 + (size_t)b * 4096;
    for (int e = tid; e < 1024; e += 256)
        ((float4*)xil)[e] = ((const float4*)xb3)[e];
    __syncthreads();

    const float* rp3 = rpre3 + (size_t)b * 4096;
    for (int e = tid; e < 4096; e += 256) {
        int o = e >> 4;
        rh[e] = fmaxf(fmaf(sc[o], rp3[e], sh[o]), 0.f);
    }
    __syncthreads();
    if (tid < 144) {
        int kk = tid >> 4, q = tid & 15;
        float s = 0.f;
        #pragma unroll
        for (int o = 0; o < 256; ++o)
            s = fmaf(wspan3[kk * 256 + o], rh[(o << 4) + q], s);
        kl[tid] = s;
    }
    __syncthreads();
    for (int e = tid; e < 4096; e += 256) {
        int o = e >> 4, q = e & 15, ho = q >> 2, wo = q & 3;
        float v = 0.f;
        const float* xo = xil + (o << 4);
        #pragma unroll
        for (int ki = 0; ki < 3; ++ki) {
            int h = ho + ki - 1;
            if (h < 0 || h >= 4) continue;
            #pragma unroll
            for (int kj = 0; kj < 3; ++kj) {
                int w = wo + kj - 1;
                if (w < 0 || w >= 4) continue;
                v = fmaf(kl[(ki * 3 + kj) * 16 + q], xo[h * 4 + w], v);
            }
        }
        rh[e] = v;
    }
    __syncthreads();

    float acc[16];
    #pragma unroll
    for (int n = 0; n < 16; ++n) acc[n] = 0.f;
    for (int i = 0; i < 16; ++i) {
        int f = tid + i * 256;
        float hv = rh[f];
        #pragma unroll
        for (int n = 0; n < 16; ++n)
            acc[n] = fmaf(hv, wfc[n * 4096 + f], acc[n]);
    }
    #pragma unroll
    for (int n = 0; n < 16; ++n) {
        float v = acc[n];
        #pragma unroll
        for (int off = 1; off < 64; off <<= 1) v += __shfl_xor(v, off);
        acc[n] = v;
    }
    const int wave = tid >> 6, lane = tid & 63;
    if (lane == 0) {
        #pragma unroll
        for (int n = 0; n < 16; ++n) red[wave][n] = acc[n];
    }
    __syncthreads();
    if (tid < 16)
        out[(size_t)b * 16 + tid] =
            red[0][tid] + red[1][tid] + red[2][tid] + red[3][tid] + bfc[tid];
}

// ---------------- launch ----------------
extern "C" void kernel_launch(void* const* d_in, const int* in_sizes, int n_in,
                              void* d_out, int out_size, void* d_ws, size_t ws_size,
                              hipStream_t stream) {
    const float* x    = (const float*)d_in[0];
    const float* Wi1  = (const float*)d_in[1];
    const float* Wr1  = (const float*)d_in[2];
    const float* g1   = (const float*)d_in[3];
    const float* be1  = (const float*)d_in[4];
    const float* Wsp1 = (const float*)d_in[5];
    const float* Wi2  = (const float*)d_in[6];
    const float* Wr2  = (const float*)d_in[7];
    const float* g2   = (const float*)d_in[8];
    const float* be2  = (const float*)d_in[9];
    const float* Wsp2 = (const float*)d_in[10];
    const float* Wi3  = (const float*)d_in[11];
    const float* Wr3  = (const float*)d_in[12];
    const float* g3   = (const float*)d_in[13];
    const float* be3  = (const float*)d_in[14];
    const float* Wsp3 = (const float*)d_in[15];
    const float* Wfc  = (const float*)d_in[16];
    const float* bfc  = (const float*)d_in[17];
    float* out = (float*)d_out;
    float* ws  = (float*)d_ws;

    float* wcat2 = ws + OFF_WCAT2;
    float* wcat3 = ws + OFF_WCAT3;
    float* sum1 = ws + OFF_SUM1; float* sqs1 = ws + OFF_SQS1;
    float* sum2 = ws + OFF_SUM2; float* sqs2 = ws + OFF_SQS2;
    float* sum3 = ws + OFF_SUM3; float* sqs3 = ws + OFF_SQS3;
    float* xi1   = ws + OFF_XI1;
    float* rpre1 = ws + OFF_RPRE1;
    float* xi2   = ws + OFF_XI2;
    float* rpre2 = ws + OFF_RPRE2;
    float* xi3   = ws + OFF_XI1;     // layer-1 region dead after f2 (kernel boundary)
    float* rpre3 = ws + OFF_RPRE1;
    unsigned short* apkh = (unsigned short*)(ws + OFF_APKH);  // aliases xi2 (dead now)
    unsigned short* apkl = (unsigned short*)(ws + OFF_APKL);

    prep_all<<<424, 256, 0, stream>>>(Wi1, Wr1, Wi2, Wr2, Wi3, Wr3, ws);
    prep_apk<<<112, 256, 0, stream>>>(Wi1, Wr1, apkh, apkl);

    p1_l1_mfma<<<1024, 512, 0, stream>>>(x, apkh, apkl, xi1, rpre1, sum1, sqs1);

    f2_kernel<<<1024, 256, 0, stream>>>(xi1, rpre1, sum1, sqs1, g1, be1, Wsp1,
                                        wcat2, xi2, rpre2, sum2, sqs2);

    f3_kernel<<<1024, 256, 0, stream>>>(xi2, rpre2, sum2, sqs2, g2, be2, Wsp2,
                                        wcat3, xi3, rpre3, sum3, sqs3);

    f4_kernel<<<1024, 256, 0, stream>>>(xi3, rpre3, sum3, sqs3, g3, be3, Wsp3,
                                        Wfc, bfc, out);
}